// Round 10
// baseline (161.680 us; speedup 1.0000x reference)
//
#include <hip/hip_runtime.h>
#include <hip/hip_bf16.h>

// GeometricFlow, round 10: 4-kernel split for per-phase attribution + prep dedup.
//   K0: pack christoffel/ricci weight records once (global, L2-resident).
//   K1: metric MLP -> g[64] per element (f32 in ws).
//   K2: christoffel hot loop (r8 math, bit-identical) -> chris bf16 in ws.
//   K3: ricci hot loop + flow MLP -> output.
// Fallback to the r8 monolith if ws_size is too small.

#define MDIM 8
#define HIDC 128
#define HIDR 256

// tanh(x) ~ x * (TC0 + u*(TC1 + u*(TC2 + u*TC3))), u = x^2  (|x| <~ 0.8)
#define TC0 ( 0.986156f)
#define TC1 (-0.255552f)
#define TC2 ( 0.0439642f)
#define TC3 (-0.0029314f)

typedef float f2 __attribute__((ext_vector_type(2)));

// ---- ws layout (bytes) ----
#define WS_G_OFF      0u                  // f32 [B*64]    (1 MB)
#define WS_CHRIS_OFF  (1u << 20)          // bf16 [B*512]  (4 MB)
#define WS_CW_OFF     (5u << 20)          // f32 [512]     (2 KB)  christoffel weights
#define WS_RW_OFF     ((5u << 20) + 4096u)// f32 [2560]    (10 KB) ricci weights
#define WS_NEEDED     ((size_t)((5u << 20) + 4096u + 10240u))

// ---------------- K0: one-time weight packing ----------------
__global__ void k0_pack(const float* __restrict__ Wc1, const float* __restrict__ Wc2,
                        const float* __restrict__ Wr1, const float* __restrict__ Wr2,
                        float* __restrict__ ws)
{
    const int t = threadIdx.x;
    float4* cw = (float4*)(ws + (WS_CW_OFF >> 2));
    float4* rw = (float4*)(ws + (WS_RW_OFF >> 2));
    if (t < 64) {   // christoffel: per h2 record = {wy0,wy1,wz0,wz1 | ww0,ww1,wo0,wo1}
        const int h = 2 * t;
        cw[t * 2 + 0] = make_float4(Wc1[8 * 128 + h], Wc1[8 * 128 + h + 1],
                                    Wc1[9 * 128 + h], Wc1[9 * 128 + h + 1]);
        cw[t * 2 + 1] = make_float4(Wc1[10 * 128 + h], Wc1[10 * 128 + h + 1],
                                    Wc2[h], Wc2[h + 1]);
    }
    if (t < 128) {  // ricci: per h2 record = {wg,c0 | c1,c2 | c3,c4 | c5,c6 | c7,wr2}
        const int h = 2 * t;
        float v[20];
        v[0] = Wr1[8 * 256 + h]; v[1] = Wr1[8 * 256 + h + 1];
        #pragma unroll
        for (int k = 0; k < 8; ++k) {
            v[2 + 2 * k] = Wr1[(9 + k) * 256 + h];
            v[3 + 2 * k] = Wr1[(9 + k) * 256 + h + 1];
        }
        v[18] = Wr2[h]; v[19] = Wr2[h + 1];
        #pragma unroll
        for (int q = 0; q < 5; ++q)
            rw[t * 5 + q] = make_float4(v[4 * q], v[4 * q + 1], v[4 * q + 2], v[4 * q + 3]);
    }
}

// ---------------- K1: metric network -> g ----------------
__global__ void k1_metric(const float* __restrict__ points,
                          const float* __restrict__ Wm1, const float* __restrict__ bm1,
                          const float* __restrict__ Wm2, const float* __restrict__ bm2,
                          float* __restrict__ ws)
{
    __shared__ float hmL[128];
    const int b = blockIdx.x, t = threadIdx.x;   // 64 threads
    float pd[8];
    #pragma unroll
    for (int d = 0; d < 8; ++d) pd[d] = points[b * 8 + d];
    #pragma unroll
    for (int r = 0; r < 2; ++r) {
        const int h = t + 64 * r;
        float a = bm1[h];
        #pragma unroll
        for (int d = 0; d < 8; ++d) a = fmaf(pd[d], Wm1[d * 128 + h], a);
        hmL[h] = fmaxf(a, 0.f);
    }
    __syncthreads();
    float acc = bm2[t];
    #pragma unroll 16
    for (int h = 0; h < 128; ++h) acc = fmaf(hmL[h], Wm2[h * 64 + t], acc);
    (ws + (WS_G_OFF >> 2))[b * 64 + t] = acc;
}

// ---------------- K2: christoffel hot loop ----------------
__global__ __launch_bounds__(256, 8) void k2_chris(
    const float* __restrict__ points,
    const float* __restrict__ Wc1, const float* __restrict__ bc1,
    const float* __restrict__ bc2,
    float* __restrict__ ws)
{
    __shared__ float4 cwL[128];   // 64 h2 x 2 float4
    __shared__ f2     baseC[64];
    __shared__ float  gL[64];
    const int b = blockIdx.x, tid = threadIdx.x;
    const float*  gG  = ws + (WS_G_OFF >> 2);
    const float4* cwG = (const float4*)(ws + (WS_CW_OFF >> 2));
    __hip_bfloat16* chrisG = (__hip_bfloat16*)((char*)ws + WS_CHRIS_OFF);

    if (tid < 128) cwL[tid] = cwG[tid];
    if (tid < 64)  gL[tid] = gG[b * 64 + tid];
    if (tid >= 128) {
        const int h = tid - 128;
        float a = bc1[h];
        #pragma unroll
        for (int d = 0; d < 8; ++d) a = fmaf(points[b * 8 + d], Wc1[d * 128 + h], a);
        ((float*)baseC)[h] = a;
    }
    __syncthreads();

    const int t0 = tid;
    const int i0 = t0 >> 6, j0 = (t0 >> 3) & 7, k0 = t0 & 7;
    const int i1 = i0 + 4;
    const float gij0 = gL[i0 * 8 + j0];
    const float gij1 = gL[i1 * 8 + j0];
    const float gjk  = gL[j0 * 8 + k0];
    const float gki0 = gL[k0 * 8 + i0];
    const float gki1 = gL[k0 * 8 + i1];
    const f2 GJK  = {gjk,  gjk};
    const f2 GIJ0 = {gij0, gij0};
    const f2 GIJ1 = {gij1, gij1};
    const f2 GKI0 = {gki0, gki0};
    const f2 GKI1 = {gki1, gki1};
    const f2 C3 = {TC3, TC3}, C2v = {TC2, TC2};
    const f2 C1v = {TC1, TC1}, C0v = {TC0, TC0};

    f2 a0 = {0.f, 0.f}, a1 = {0.f, 0.f};
    #pragma unroll 4
    for (int h2 = 0; h2 < HIDC / 2; ++h2) {
        const float4 q0 = cwL[h2 * 2 + 0];
        const float4 q1 = cwL[h2 * 2 + 1];
        const f2 B  = baseC[h2];
        const f2 WY = {q0.x, q0.y};
        const f2 WZ = {q0.z, q0.w};
        const f2 WW = {q1.x, q1.y};
        const f2 WO = {q1.z, q1.w};
        const f2 S  = __builtin_elementwise_fma(GJK, WZ, B);
        const f2 X0 = __builtin_elementwise_fma(
                          GIJ0, WY, __builtin_elementwise_fma(GKI0, WW, S));
        const f2 X1 = __builtin_elementwise_fma(
                          GIJ1, WY, __builtin_elementwise_fma(GKI1, WW, S));
        const f2 U0 = X0 * X0;
        const f2 U1 = X1 * X1;
        f2 T0 = __builtin_elementwise_fma(U0, C3, C2v);
        T0 = __builtin_elementwise_fma(U0, T0, C1v);
        T0 = __builtin_elementwise_fma(U0, T0, C0v);
        f2 T1 = __builtin_elementwise_fma(U1, C3, C2v);
        T1 = __builtin_elementwise_fma(U1, T1, C1v);
        T1 = __builtin_elementwise_fma(U1, T1, C0v);
        a0 = __builtin_elementwise_fma(WO, X0 * T0, a0);
        a1 = __builtin_elementwise_fma(WO, X1 * T1, a1);
    }
    const float cb = bc2[0];
    chrisG[b * 512 + t0]       = __float2bfloat16(a0.x + a0.y + cb);
    chrisG[b * 512 + t0 + 256] = __float2bfloat16(a1.x + a1.y + cb);
}

// ---------------- K3: ricci + flow + output ----------------
__global__ __launch_bounds__(256, 8) void k3_ricci_flow(
    const float* __restrict__ points,
    const float* __restrict__ Wr1, const float* __restrict__ br1,
    const float* __restrict__ br2,
    const float* __restrict__ Wf1, const float* __restrict__ bf1v,
    const float* __restrict__ Wf2, const float* __restrict__ bf2v,
    float* __restrict__ ws, float* __restrict__ outp)
{
    __shared__ float4   rwL[640];     // 128 h2 x 5 float4 (10 KB)
    __shared__ f2       base2R[128];
    __shared__ unsigned chrisL[256];  // 512 bf16
    __shared__ float    gL[64];
    __shared__ float    pL[8];
    __shared__ float    ric[64];
    __shared__ float    flowin[16];
    __shared__ float    fh[128];
    const int b = blockIdx.x, tid = threadIdx.x;
    const float*    gG  = ws + (WS_G_OFF >> 2);
    const float4*   rwG = (const float4*)(ws + (WS_RW_OFF >> 2));
    const unsigned* chG = (const unsigned*)((char*)ws + WS_CHRIS_OFF);

    for (int i = tid; i < 640; i += 256) rwL[i] = rwG[i];
    {
        const int h = tid;
        float a = br1[h];
        #pragma unroll
        for (int d = 0; d < 8; ++d) a = fmaf(points[b * 8 + d], Wr1[d * 256 + h], a);
        ((float*)base2R)[h] = a;
    }
    chrisL[tid] = chG[b * 256 + tid];
    if (tid < 64) gL[tid] = gG[b * 64 + tid];
    if (tid < 8)  pL[tid] = points[b * 8 + tid];
    __syncthreads();

    // ricci: 4 threads per (i,j) pair, f2-packed over (h,h+1)
    {
        const int pair = tid >> 2;
        const int part = tid & 3;
        const float gij = gL[pair];
        const f2 GIJ = {gij, gij};
        float CH[8];
        #pragma unroll
        for (int k2 = 0; k2 < 4; ++k2) {
            const unsigned u = chrisL[pair * 4 + k2];
            CH[2 * k2]     = __uint_as_float(u << 16);
            CH[2 * k2 + 1] = __uint_as_float(u & 0xFFFF0000u);
        }
        f2 acc = {0.f, 0.f};
        #pragma unroll 4
        for (int idx = 0; idx < 32; ++idx) {
            const int cur = (idx << 2) | part;     // parts hit disjoint bank quads (80B stride)
            const float4* rp = &rwL[cur * 5];
            const float4 v0 = rp[0];
            const float4 v1 = rp[1];
            const float4 v2 = rp[2];
            const float4 v3 = rp[3];
            const float4 v4 = rp[4];
            f2 x = base2R[cur];
            x = __builtin_elementwise_fma(GIJ,              (f2){v0.x, v0.y}, x);
            x = __builtin_elementwise_fma((f2){CH[0],CH[0]},(f2){v0.z, v0.w}, x);
            x = __builtin_elementwise_fma((f2){CH[1],CH[1]},(f2){v1.x, v1.y}, x);
            x = __builtin_elementwise_fma((f2){CH[2],CH[2]},(f2){v1.z, v1.w}, x);
            x = __builtin_elementwise_fma((f2){CH[3],CH[3]},(f2){v2.x, v2.y}, x);
            x = __builtin_elementwise_fma((f2){CH[4],CH[4]},(f2){v2.z, v2.w}, x);
            x = __builtin_elementwise_fma((f2){CH[5],CH[5]},(f2){v3.x, v3.y}, x);
            x = __builtin_elementwise_fma((f2){CH[6],CH[6]},(f2){v3.z, v3.w}, x);
            x = __builtin_elementwise_fma((f2){CH[7],CH[7]},(f2){v4.x, v4.y}, x);
            x = __builtin_elementwise_max(x, (f2){0.f, 0.f});
            acc = __builtin_elementwise_fma(x, (f2){v4.z, v4.w}, acc);
        }
        float s = acc.x + acc.y;
        s += __shfl_xor(s, 1);
        s += __shfl_xor(s, 2);
        if (part == 0) ric[pair] = s + br2[0];
    }
    __syncthreads();

    if (tid < MDIM) {
        float rp = 0.f;
        #pragma unroll
        for (int j = 0; j < MDIM; ++j) rp += ric[tid * 8 + j] * pL[j];
        flowin[tid]        = pL[tid];
        flowin[MDIM + tid] = rp;
    }
    __syncthreads();

    if (tid < 128) {
        float acc = bf1v[tid];
        #pragma unroll
        for (int d = 0; d < 2 * MDIM; ++d) acc += flowin[d] * Wf1[d * 128 + tid];
        fh[tid] = fmaxf(acc, 0.f);
    }
    __syncthreads();

    if (tid < MDIM) {
        float acc = bf2v[tid];
        for (int h = 0; h < 128; ++h) acc += fh[h] * Wf2[h * 8 + tid];
        outp[b * MDIM + tid] = pL[tid] + 0.01f * acc;
    }
}

// ---------------- fallback: r8 monolith (if ws too small) ----------------
__global__ __launch_bounds__(256, 8) void geoflow_mono(
    const float* __restrict__ points,
    const float* __restrict__ Wm1, const float* __restrict__ bm1,
    const float* __restrict__ Wm2, const float* __restrict__ bm2,
    const float* __restrict__ Wc1, const float* __restrict__ bc1,
    const float* __restrict__ Wc2, const float* __restrict__ bc2,
    const float* __restrict__ Wr1, const float* __restrict__ br1,
    const float* __restrict__ Wr2, const float* __restrict__ br2,
    const float* __restrict__ Wf1, const float* __restrict__ bf1v,
    const float* __restrict__ Wf2, const float* __restrict__ bf2v,
    float* __restrict__ outp)
{
    __shared__ float  p[MDIM];
    __shared__ float  hm[HIDC];
    __shared__ float  g[64];
    __shared__ float4 c4pack[64 * 3];
    __shared__ float  chris[512];
    __shared__ float4 rr[128 * 6];
    __shared__ float  ric[64];
    __shared__ float  flowin[2 * MDIM];
    __shared__ float  fh[HIDC];

    const int b   = blockIdx.x;
    const int tid = threadIdx.x;

    if (tid < MDIM) p[tid] = points[b * MDIM + tid];
    __syncthreads();

    if (tid < 128) {
        float acc = bm1[tid];
        #pragma unroll
        for (int d = 0; d < MDIM; ++d) acc += p[d] * Wm1[d * 128 + tid];
        hm[tid] = fmaxf(acc, 0.f);
    } else {
        const int h  = tid - 128;
        const int h2 = h >> 1, q = h & 1;
        float base = bc1[h];
        #pragma unroll
        for (int d = 0; d < MDIM; ++d) base += p[d] * Wc1[d * 128 + h];
        float* cf = (float*)c4pack + h2 * 12;
        cf[0 + q] = base;
        cf[2 + q] = Wc1[8  * 128 + h];
        cf[4 + q] = Wc1[9  * 128 + h];
        cf[6 + q] = Wc1[10 * 128 + h];
        cf[8 + q] = Wc2[h];
    }
    __syncthreads();

    {
        const int h  = tid;
        const int h2 = h >> 1, q = h & 1;
        float base2 = br1[h];
        #pragma unroll
        for (int d = 0; d < MDIM; ++d) base2 += p[d] * Wr1[d * HIDR + h];
        float* rf = (float*)rr + h2 * 24;
        rf[0 + q]  = base2;
        rf[2 + q]  = Wr1[8 * HIDR + h];
        #pragma unroll
        for (int k = 0; k < 8; ++k)
            rf[4 + 2 * k + q] = Wr1[(9 + k) * HIDR + h];
        rf[20 + q] = Wr2[h];
    }
    if (tid < 64) {
        float acc = bm2[tid];
        for (int h = 0; h < 128; ++h) acc += hm[h] * Wm2[h * 64 + tid];
        g[tid] = acc;
    }
    __syncthreads();

    {
        const int t0 = tid;
        const int i0 = t0 >> 6, j0 = (t0 >> 3) & 7, k0 = t0 & 7;
        const int i1 = i0 + 4;
        const float gij0 = g[i0 * 8 + j0];
        const float gij1 = g[i1 * 8 + j0];
        const float gjk  = g[j0 * 8 + k0];
        const float gki0 = g[k0 * 8 + i0];
        const float gki1 = g[k0 * 8 + i1];
        const f2 GJK  = {gjk,  gjk};
        const f2 GIJ0 = {gij0, gij0};
        const f2 GIJ1 = {gij1, gij1};
        const f2 GKI0 = {gki0, gki0};
        const f2 GKI1 = {gki1, gki1};
        const f2 C3 = {TC3, TC3}, C2v = {TC2, TC2};
        const f2 C1v = {TC1, TC1}, C0v = {TC0, TC0};
        f2 a0 = {0.f, 0.f}, a1 = {0.f, 0.f};
        #pragma unroll 4
        for (int h2 = 0; h2 < HIDC / 2; ++h2) {
            const float4 q0 = c4pack[h2 * 3 + 0];
            const float4 q1 = c4pack[h2 * 3 + 1];
            const f2 WO = ((const f2*)c4pack)[h2 * 6 + 4];
            const f2 B  = {q0.x, q0.y};
            const f2 WY = {q0.z, q0.w};
            const f2 WZ = {q1.x, q1.y};
            const f2 WW = {q1.z, q1.w};
            const f2 S  = __builtin_elementwise_fma(GJK, WZ, B);
            const f2 X0 = __builtin_elementwise_fma(
                              GIJ0, WY, __builtin_elementwise_fma(GKI0, WW, S));
            const f2 X1 = __builtin_elementwise_fma(
                              GIJ1, WY, __builtin_elementwise_fma(GKI1, WW, S));
            const f2 U0 = X0 * X0;
            const f2 U1 = X1 * X1;
            f2 T0 = __builtin_elementwise_fma(U0, C3, C2v);
            T0 = __builtin_elementwise_fma(U0, T0, C1v);
            T0 = __builtin_elementwise_fma(U0, T0, C0v);
            f2 T1 = __builtin_elementwise_fma(U1, C3, C2v);
            T1 = __builtin_elementwise_fma(U1, T1, C1v);
            T1 = __builtin_elementwise_fma(U1, T1, C0v);
            a0 = __builtin_elementwise_fma(WO, X0 * T0, a0);
            a1 = __builtin_elementwise_fma(WO, X1 * T1, a1);
        }
        const float cb = bc2[0];
        chris[t0]       = a0.x + a0.y + cb;
        chris[t0 + 256] = a1.x + a1.y + cb;
    }
    __syncthreads();

    {
        const int pair = tid >> 2;
        const int part = tid & 3;
        const float gij = g[pair];
        const f2 GIJ = {gij, gij};
        f2 CH[8];
        #pragma unroll
        for (int k = 0; k < 8; ++k) {
            const float c = chris[pair * 8 + k];
            CH[k] = (f2){c, c};
        }
        f2 acc = {0.f, 0.f};
        #pragma unroll 4
        for (int idx = 0; idx < 32; ++idx) {
            const int h2 = (idx << 2) | part;
            const float4* rp = &rr[h2 * 6];
            const float4 v0 = rp[0];
            const float4 v1 = rp[1];
            const float4 v2 = rp[2];
            const float4 v3 = rp[3];
            const float4 v4 = rp[4];
            const f2 WR2 = ((const f2*)rp)[10];
            f2 x = (f2){v0.x, v0.y};
            x = __builtin_elementwise_fma(GIJ,   (f2){v0.z, v0.w}, x);
            x = __builtin_elementwise_fma(CH[0], (f2){v1.x, v1.y}, x);
            x = __builtin_elementwise_fma(CH[1], (f2){v1.z, v1.w}, x);
            x = __builtin_elementwise_fma(CH[2], (f2){v2.x, v2.y}, x);
            x = __builtin_elementwise_fma(CH[3], (f2){v2.z, v2.w}, x);
            x = __builtin_elementwise_fma(CH[4], (f2){v3.x, v3.y}, x);
            x = __builtin_elementwise_fma(CH[5], (f2){v3.z, v3.w}, x);
            x = __builtin_elementwise_fma(CH[6], (f2){v4.x, v4.y}, x);
            x = __builtin_elementwise_fma(CH[7], (f2){v4.z, v4.w}, x);
            x = __builtin_elementwise_max(x, (f2){0.f, 0.f});
            acc = __builtin_elementwise_fma(x, WR2, acc);
        }
        float s = acc.x + acc.y;
        s += __shfl_xor(s, 1);
        s += __shfl_xor(s, 2);
        if (part == 0) ric[pair] = s + br2[0];
    }
    __syncthreads();

    if (tid < MDIM) {
        float rp = 0.f;
        #pragma unroll
        for (int j = 0; j < MDIM; ++j) rp += ric[tid * 8 + j] * p[j];
        flowin[tid]        = p[tid];
        flowin[MDIM + tid] = rp;
    }
    __syncthreads();

    if (tid < 128) {
        float acc = bf1v[tid];
        #pragma unroll
        for (int d = 0; d < 2 * MDIM; ++d) acc += flowin[d] * Wf1[d * 128 + tid];
        fh[tid] = fmaxf(acc, 0.f);
    }
    __syncthreads();

    if (tid < MDIM) {
        float acc = bf2v[tid];
        for (int h = 0; h < 128; ++h) acc += fh[h] * Wf2[h * 8 + tid];
        outp[b * MDIM + tid] = p[tid] + 0.01f * acc;
    }
}

extern "C" void kernel_launch(void* const* d_in, const int* in_sizes, int n_in,
                              void* d_out, int out_size, void* d_ws, size_t ws_size,
                              hipStream_t stream) {
    const float* points = (const float*)d_in[0];
    const float* Wm1 = (const float*)d_in[1];
    const float* bm1 = (const float*)d_in[2];
    const float* Wm2 = (const float*)d_in[3];
    const float* bm2 = (const float*)d_in[4];
    const float* Wc1 = (const float*)d_in[5];
    const float* bc1 = (const float*)d_in[6];
    const float* Wc2 = (const float*)d_in[7];
    const float* bc2 = (const float*)d_in[8];
    const float* Wr1 = (const float*)d_in[9];
    const float* br1 = (const float*)d_in[10];
    const float* Wr2 = (const float*)d_in[11];
    const float* br2 = (const float*)d_in[12];
    const float* Wf1 = (const float*)d_in[13];
    const float* bf1v = (const float*)d_in[14];
    const float* Wf2 = (const float*)d_in[15];
    const float* bf2v = (const float*)d_in[16];
    float* outp = (float*)d_out;

    const int BATCH = in_sizes[0] / MDIM;   // 4096

    if (ws_size >= WS_NEEDED) {
        float* ws = (float*)d_ws;
        k0_pack<<<1, 128, 0, stream>>>(Wc1, Wc2, Wr1, Wr2, ws);
        k1_metric<<<BATCH, 64, 0, stream>>>(points, Wm1, bm1, Wm2, bm2, ws);
        k2_chris<<<BATCH, 256, 0, stream>>>(points, Wc1, bc1, bc2, ws);
        k3_ricci_flow<<<BATCH, 256, 0, stream>>>(points, Wr1, br1, br2,
                                                 Wf1, bf1v, Wf2, bf2v, ws, outp);
    } else {
        geoflow_mono<<<BATCH, 256, 0, stream>>>(
            points, Wm1, bm1, Wm2, bm2, Wc1, bc1, Wc2, bc2,
            Wr1, br1, Wr2, br2, Wf1, bf1v, Wf2, bf2v, outp);
    }
}